// Round 1
// baseline (724.101 us; speedup 1.0000x reference)
//
#include <hip/hip_runtime.h>
#include <hip/hip_bf16.h>

#define B_ROWS 1024
#define OBS_D  512
#define ACT_D  64
#define KD     128
#define CAT_D  192
#define CAP    131072

// ---------------------------------------------------------------------------
// Kernel 1: fused MLP  obs -> pred -> L2norm -> concat(action) -> t1(relu) -> t2
// Writes h (1024x128) and hnorm (1024) = ||h_row|| used as softmax shift.
// ---------------------------------------------------------------------------
#define MLP_ROWS 8

__global__ __launch_bounds__(256) void mlp_kernel(
    const float* __restrict__ obs, const float* __restrict__ action,
    const float* __restrict__ pred_W, const float* __restrict__ pred_b,
    const float* __restrict__ t1_W, const float* __restrict__ t1_b,
    const float* __restrict__ t2_W, const float* __restrict__ t2_b,
    float* __restrict__ h_out, float* __restrict__ hnorm) {
  __shared__ float s_obs[MLP_ROWS][OBS_D];
  __shared__ float s_in[MLP_ROWS][KD];
  __shared__ float s_cat[MLP_ROWS][CAT_D];
  __shared__ float s_h1[MLP_ROWS][KD];
  __shared__ float s_ho[MLP_ROWS][KD];
  __shared__ float s_norm[MLP_ROWS];

  const int t = threadIdx.x;
  const int row0 = blockIdx.x * MLP_ROWS;

  // stage obs rows (coalesced float4)
  {
    const float4* g = (const float4*)(obs + (size_t)row0 * OBS_D);
    float4* s = (float4*)&s_obs[0][0];
    for (int i = t; i < MLP_ROWS * OBS_D / 4; i += 256) s[i] = g[i];
  }
  __syncthreads();

  const int k  = t & 127;   // output column
  const int r0 = t >> 7;    // 0/1; thread covers rows r0, r0+2, r0+4, r0+6

  // phase A: inpt = obs @ pred_W.T + pred_b
  {
    float acc[4] = {0.f, 0.f, 0.f, 0.f};
    const float4* w4 = (const float4*)(pred_W + (size_t)k * OBS_D);
    for (int d4 = 0; d4 < OBS_D / 4; ++d4) {
      float4 wv = w4[d4];
      #pragma unroll
      for (int p = 0; p < 4; ++p) {
        const float* sr = &s_obs[r0 + 2 * p][d4 * 4];
        acc[p] += wv.x * sr[0] + wv.y * sr[1] + wv.z * sr[2] + wv.w * sr[3];
      }
    }
    float b = pred_b[k];
    #pragma unroll
    for (int p = 0; p < 4; ++p) s_in[r0 + 2 * p][k] = acc[p] + b;
  }
  __syncthreads();

  // row L2 norms of inpt (8 rows, 32 threads each)
  {
    int r = t >> 5, l = t & 31;
    float ss = 0.f;
    #pragma unroll
    for (int j = 0; j < 4; ++j) { float v = s_in[r][l + 32 * j]; ss += v * v; }
    #pragma unroll
    for (int off = 16; off; off >>= 1) ss += __shfl_down(ss, off, 32);
    if (l == 0) s_norm[r] = fmaxf(sqrtf(ss), 1e-12f);
  }
  __syncthreads();

  // concat normalized inpt with action
  for (int i = t; i < MLP_ROWS * CAT_D; i += 256) {
    int r = i / CAT_D, c = i % CAT_D;
    float v = (c < KD) ? s_in[r][c] / s_norm[r]
                       : action[(size_t)(row0 + r) * ACT_D + (c - KD)];
    s_cat[r][c] = v;
  }
  __syncthreads();

  // phase B: h1 = relu(cat @ t1_W.T + t1_b)
  {
    float acc[4] = {0.f, 0.f, 0.f, 0.f};
    const float4* w4 = (const float4*)(t1_W + (size_t)k * CAT_D);
    for (int d4 = 0; d4 < CAT_D / 4; ++d4) {
      float4 wv = w4[d4];
      #pragma unroll
      for (int p = 0; p < 4; ++p) {
        const float* sr = &s_cat[r0 + 2 * p][d4 * 4];
        acc[p] += wv.x * sr[0] + wv.y * sr[1] + wv.z * sr[2] + wv.w * sr[3];
      }
    }
    float b = t1_b[k];
    #pragma unroll
    for (int p = 0; p < 4; ++p) s_h1[r0 + 2 * p][k] = fmaxf(acc[p] + b, 0.f);
  }
  __syncthreads();

  // phase C: h = h1 @ t2_W.T + t2_b
  {
    float acc[4] = {0.f, 0.f, 0.f, 0.f};
    const float4* w4 = (const float4*)(t2_W + (size_t)k * KD);
    for (int d4 = 0; d4 < KD / 4; ++d4) {
      float4 wv = w4[d4];
      #pragma unroll
      for (int p = 0; p < 4; ++p) {
        const float* sr = &s_h1[r0 + 2 * p][d4 * 4];
        acc[p] += wv.x * sr[0] + wv.y * sr[1] + wv.z * sr[2] + wv.w * sr[3];
      }
    }
    float b = t2_b[k];
    #pragma unroll
    for (int p = 0; p < 4; ++p) {
      float hv = acc[p] + b;
      s_ho[r0 + 2 * p][k] = hv;
      h_out[(size_t)(row0 + r0 + 2 * p) * KD + k] = hv;
    }
  }
  __syncthreads();

  // ||h|| per row (softmax exponent shift; any per-row constant is valid)
  {
    int r = t >> 5, l = t & 31;
    float ss = 0.f;
    #pragma unroll
    for (int j = 0; j < 4; ++j) { float v = s_ho[r][l + 32 * j]; ss += v * v; }
    #pragma unroll
    for (int off = 16; off; off >>= 1) ss += __shfl_down(ss, off, 32);
    if (l == 0) hnorm[row0 + r] = sqrtf(ss);
  }
}

// ---------------------------------------------------------------------------
// Kernel 2: scores + shifted-exp + (s, q) partial sums.
//   qs = (sum_i e^{ws_i - M} v_i) / (sum_i e^{ws_i - M}),  M = ||h||/tau
// Block: 64 rows x keys_per_block keys, staging 64-key chunks in LDS.
// Thread: 4 keys x 4 rows (16 FMA per 8 LDS float4 reads).
// ---------------------------------------------------------------------------
#define TB 64
#define KG 64
#define SPAD 132   // 128 + 4: float4-aligned, spreads banks

__global__ __launch_bounds__(256) void score_kernel(
    const float* __restrict__ h, const float* __restrict__ hnorm,
    const float* __restrict__ keys, const float* __restrict__ values,
    const float* __restrict__ log_temp,
    float* __restrict__ accum, int keys_per_block) {
  __shared__ float s_h[TB][SPAD];
  __shared__ float s_k[KG][SPAD];
  __shared__ float s_v[KG];

  const int t  = threadIdx.x;
  const int kq = t & 15;   // key-quad id (keys kq + 16j)
  const int rq = t >> 4;   // row-quad id (rows rq*4 + i), 0..15
  const int row0 = blockIdx.y * TB;
  const size_t key0 = (size_t)blockIdx.x * (size_t)keys_per_block;
  const float inv_temp = __expf(-log_temp[0]);

  // stage h tile
  {
    const float4* g = (const float4*)(h + (size_t)row0 * KD);
    for (int i = t; i < TB * KD / 4; i += 256) {
      int r = i >> 5, d4 = i & 31;
      *(float4*)&s_h[r][d4 * 4] = g[i];
    }
  }

  float m[4];
  #pragma unroll
  for (int i = 0; i < 4; ++i) m[i] = hnorm[row0 + rq * 4 + i] * inv_temp;

  float s_acc[4] = {0.f, 0.f, 0.f, 0.f};
  float q_acc[4] = {0.f, 0.f, 0.f, 0.f};

  for (int kg = 0; kg < keys_per_block; kg += KG) {
    __syncthreads();  // also covers initial h staging
    {
      const float4* g = (const float4*)(keys + (key0 + kg) * KD);
      for (int i = t; i < KG * KD / 4; i += 256) {
        int ki = i >> 5, d4 = i & 31;
        *(float4*)&s_k[ki][d4 * 4] = g[i];
      }
      if (t < KG) s_v[t] = values[key0 + kg + t];
    }
    __syncthreads();

    float sc[4][4];
    #pragma unroll
    for (int i = 0; i < 4; ++i)
      #pragma unroll
      for (int j = 0; j < 4; ++j) sc[i][j] = 0.f;

    for (int d = 0; d < KD; d += 4) {
      float4 kv[4], hv[4];
      #pragma unroll
      for (int j = 0; j < 4; ++j) kv[j] = *(const float4*)&s_k[kq + 16 * j][d];
      #pragma unroll
      for (int i = 0; i < 4; ++i) hv[i] = *(const float4*)&s_h[rq * 4 + i][d];
      #pragma unroll
      for (int i = 0; i < 4; ++i)
        #pragma unroll
        for (int j = 0; j < 4; ++j)
          sc[i][j] += hv[i].x * kv[j].x + hv[i].y * kv[j].y
                    + hv[i].z * kv[j].z + hv[i].w * kv[j].w;
    }

    #pragma unroll
    for (int j = 0; j < 4; ++j) {
      float v = s_v[kq + 16 * j];
      #pragma unroll
      for (int i = 0; i < 4; ++i) {
        float e = __expf(fmaf(sc[i][j], inv_temp, -m[i]));
        s_acc[i] += e;
        q_acc[i] += e * v;
      }
    }
  }

  // reduce across the 16 lanes sharing a row-quad (contiguous lanes), then atomics
  #pragma unroll
  for (int i = 0; i < 4; ++i) {
    float s = s_acc[i], q = q_acc[i];
    #pragma unroll
    for (int off = 8; off; off >>= 1) {
      s += __shfl_down(s, off, 16);
      q += __shfl_down(q, off, 16);
    }
    if (kq == 0) {
      atomicAdd(&accum[(size_t)(row0 + rq * 4 + i) * 2 + 0], s);
      atomicAdd(&accum[(size_t)(row0 + rq * 4 + i) * 2 + 1], q);
    }
  }
}

// ---------------------------------------------------------------------------
// Kernel 3: out = q / s
// ---------------------------------------------------------------------------
__global__ void finalize_kernel(const float* __restrict__ accum,
                                float* __restrict__ out) {
  int b = blockIdx.x * 256 + threadIdx.x;
  if (b < B_ROWS) out[b] = accum[(size_t)b * 2 + 1] / accum[(size_t)b * 2 + 0];
}

// ---------------------------------------------------------------------------
extern "C" void kernel_launch(void* const* d_in, const int* in_sizes, int n_in,
                              void* d_out, int out_size, void* d_ws, size_t ws_size,
                              hipStream_t stream) {
  const float* obs     = (const float*)d_in[0];
  const float* action  = (const float*)d_in[1];
  const float* pred_W  = (const float*)d_in[2];
  const float* pred_b  = (const float*)d_in[3];
  const float* t1_W    = (const float*)d_in[4];
  const float* t1_b    = (const float*)d_in[5];
  const float* t2_W    = (const float*)d_in[6];
  const float* t2_b    = (const float*)d_in[7];
  const float* keys    = (const float*)d_in[8];
  const float* values  = (const float*)d_in[9];
  const float* log_temp = (const float*)d_in[10];
  float* out = (float*)d_out;

  float* h     = (float*)d_ws;            // 1024*128 f32
  float* hnorm = h + (size_t)B_ROWS * KD; // 1024 f32
  float* accum = hnorm + B_ROWS;          // 1024*2 f32 (s, q)

  hipMemsetAsync(accum, 0, (size_t)B_ROWS * 2 * sizeof(float), stream);

  hipLaunchKernelGGL(mlp_kernel, dim3(B_ROWS / MLP_ROWS), dim3(256), 0, stream,
                     obs, action, pred_W, pred_b, t1_W, t1_b, t2_W, t2_b,
                     h, hnorm);

  const int C_CHUNKS = 32;
  hipLaunchKernelGGL(score_kernel, dim3(C_CHUNKS, B_ROWS / TB), dim3(256), 0,
                     stream, h, hnorm, keys, values, log_temp, accum,
                     CAP / C_CHUNKS);

  hipLaunchKernelGGL(finalize_kernel, dim3(4), dim3(256), 0, stream, accum, out);
}

// Round 2
// 264.697 us; speedup vs baseline: 2.7356x; 2.7356x over previous
//
#include <hip/hip_runtime.h>
#include <hip/hip_bf16.h>

#define B_ROWS 1024
#define OBS_D  512
#define ACT_D  64
#define KD     128
#define CAT_D  192
#define CAP    131072

typedef __attribute__((ext_vector_type(8))) short bf16x8;
typedef __attribute__((ext_vector_type(4))) float f32x4;
typedef __attribute__((ext_vector_type(4))) unsigned short us4;

static __device__ __forceinline__ unsigned short f2bf(float x) {
  unsigned u = __float_as_uint(x);
  return (unsigned short)((u + 0x7fffu + ((u >> 16) & 1u)) >> 16);
}

static __device__ __forceinline__ f32x4 mfma16(bf16x8 a, bf16x8 b, f32x4 c) {
  return __builtin_amdgcn_mfma_f32_16x16x32_bf16(a, b, c, 0, 0, 0);
}

// ---------------------------------------------------------------------------
// Kernel 1: fused MLP. Writes h_scaled = h * (1/tau * log2 e)  and
// hnorm = ||h_scaled|| (softmax shift in the exp2 domain).
// ---------------------------------------------------------------------------
#define MLP_ROWS 8

__global__ __launch_bounds__(256) void mlp_kernel(
    const float* __restrict__ obs, const float* __restrict__ action,
    const float* __restrict__ pred_W, const float* __restrict__ pred_b,
    const float* __restrict__ t1_W, const float* __restrict__ t1_b,
    const float* __restrict__ t2_W, const float* __restrict__ t2_b,
    const float* __restrict__ log_temp,
    float* __restrict__ h_out, float* __restrict__ hnorm) {
  __shared__ float s_obs[MLP_ROWS][OBS_D];
  __shared__ float s_in[MLP_ROWS][KD];
  __shared__ float s_cat[MLP_ROWS][CAT_D];
  __shared__ float s_h1[MLP_ROWS][KD];
  __shared__ float s_ho[MLP_ROWS][KD];
  __shared__ float s_norm[MLP_ROWS];

  const int t = threadIdx.x;
  const int row0 = blockIdx.x * MLP_ROWS;
  const float SCALE = expf(-log_temp[0]) * 1.44269504088896f;

  {
    const float4* g = (const float4*)(obs + (size_t)row0 * OBS_D);
    float4* s = (float4*)&s_obs[0][0];
    for (int i = t; i < MLP_ROWS * OBS_D / 4; i += 256) s[i] = g[i];
  }
  __syncthreads();

  const int k  = t & 127;
  const int r0 = t >> 7;

  {
    float acc[4] = {0.f, 0.f, 0.f, 0.f};
    const float4* w4 = (const float4*)(pred_W + (size_t)k * OBS_D);
    for (int d4 = 0; d4 < OBS_D / 4; ++d4) {
      float4 wv = w4[d4];
      #pragma unroll
      for (int p = 0; p < 4; ++p) {
        const float* sr = &s_obs[r0 + 2 * p][d4 * 4];
        acc[p] += wv.x * sr[0] + wv.y * sr[1] + wv.z * sr[2] + wv.w * sr[3];
      }
    }
    float b = pred_b[k];
    #pragma unroll
    for (int p = 0; p < 4; ++p) s_in[r0 + 2 * p][k] = acc[p] + b;
  }
  __syncthreads();

  {
    int r = t >> 5, l = t & 31;
    float ss = 0.f;
    #pragma unroll
    for (int j = 0; j < 4; ++j) { float v = s_in[r][l + 32 * j]; ss += v * v; }
    #pragma unroll
    for (int off = 16; off; off >>= 1) ss += __shfl_down(ss, off, 32);
    if (l == 0) s_norm[r] = fmaxf(sqrtf(ss), 1e-12f);
  }
  __syncthreads();

  for (int i = t; i < MLP_ROWS * CAT_D; i += 256) {
    int r = i / CAT_D, c = i % CAT_D;
    float v = (c < KD) ? s_in[r][c] / s_norm[r]
                       : action[(size_t)(row0 + r) * ACT_D + (c - KD)];
    s_cat[r][c] = v;
  }
  __syncthreads();

  {
    float acc[4] = {0.f, 0.f, 0.f, 0.f};
    const float4* w4 = (const float4*)(t1_W + (size_t)k * CAT_D);
    for (int d4 = 0; d4 < CAT_D / 4; ++d4) {
      float4 wv = w4[d4];
      #pragma unroll
      for (int p = 0; p < 4; ++p) {
        const float* sr = &s_cat[r0 + 2 * p][d4 * 4];
        acc[p] += wv.x * sr[0] + wv.y * sr[1] + wv.z * sr[2] + wv.w * sr[3];
      }
    }
    float b = t1_b[k];
    #pragma unroll
    for (int p = 0; p < 4; ++p) s_h1[r0 + 2 * p][k] = fmaxf(acc[p] + b, 0.f);
  }
  __syncthreads();

  {
    float acc[4] = {0.f, 0.f, 0.f, 0.f};
    const float4* w4 = (const float4*)(t2_W + (size_t)k * KD);
    for (int d4 = 0; d4 < KD / 4; ++d4) {
      float4 wv = w4[d4];
      #pragma unroll
      for (int p = 0; p < 4; ++p) {
        const float* sr = &s_h1[r0 + 2 * p][d4 * 4];
        acc[p] += wv.x * sr[0] + wv.y * sr[1] + wv.z * sr[2] + wv.w * sr[3];
      }
    }
    float b = t2_b[k];
    #pragma unroll
    for (int p = 0; p < 4; ++p) {
      float hv = (acc[p] + b) * SCALE;
      s_ho[r0 + 2 * p][k] = hv;
      h_out[(size_t)(row0 + r0 + 2 * p) * KD + k] = hv;
    }
  }
  __syncthreads();

  {
    int r = t >> 5, l = t & 31;
    float ss = 0.f;
    #pragma unroll
    for (int j = 0; j < 4; ++j) { float v = s_ho[r][l + 32 * j]; ss += v * v; }
    #pragma unroll
    for (int off = 16; off; off >>= 1) ss += __shfl_down(ss, off, 32);
    if (l == 0) hnorm[row0 + r] = sqrtf(ss);
  }
}

// ---------------------------------------------------------------------------
// Kernel P: keys fp32 -> keys2 (per-128-key chunk, hi/lo bf16 planes,
// XOR-swizzled layout so score staging is a linear global_load_lds).
// chunk image (65536 B): [plane hi 32768][plane lo 32768],
// element (r,k): byte = r*256 + ((k*2) ^ ((r&7)<<4))   (XOR hits bits 4-6)
// ---------------------------------------------------------------------------
__global__ __launch_bounds__(256) void preconv_kernel(
    const float* __restrict__ keys, char* __restrict__ keys2) {
  size_t i = (size_t)blockIdx.x * 256 + threadIdx.x;  // float4 index
  int key = (int)(i >> 5);
  int d4  = (int)(i & 31);
  float4 x = ((const float4*)keys)[i];
  float xs[4] = {x.x, x.y, x.z, x.w};
  us4 hi4, lo4;
  #pragma unroll
  for (int j = 0; j < 4; ++j) {
    unsigned short hb = f2bf(xs[j]);
    float hf = __uint_as_float((unsigned)hb << 16);
    hi4[j] = hb;
    lo4[j] = f2bf(xs[j] - hf);
  }
  int chunk = key >> 7;
  int r = key & 127;
  int off = r * 256 + ((d4 * 8) ^ ((r & 7) << 4));
  char* base = keys2 + (size_t)chunk * 65536;
  *(us4*)(base + off) = hi4;
  *(us4*)(base + 32768 + off) = lo4;
}

// ---------------------------------------------------------------------------
// Kernel 2 (MFMA path): block = 64 rows x 4096 keys, 4 waves in a 2x2 grid
// of 32row x 64col tiles. A (h hi/lo) in registers across all chunks; B (keys)
// staged per 128-key chunk via global_load_lds from the pre-swizzled image.
// C = Ahi*Bhi + Alo*Bhi + Ahi*Blo (3-term bf16 split ~ fp32 precision).
// ---------------------------------------------------------------------------
#define KG2 128

__global__ __launch_bounds__(256, 2) void score_mfma_kernel(
    const float* __restrict__ h, const float* __restrict__ hnorm,
    const char* __restrict__ keys2, const float* __restrict__ values,
    float* __restrict__ accum, int chunks_per_block) {
  __shared__ short s_k[2][KG2][128];   // 64 KB, swizzled image
  __shared__ float s_v[KG2];

  const int t = threadIdx.x;
  const int w = t >> 6, l = t & 63;
  const int lr = l & 15, lk = l >> 4;
  const int row0 = blockIdx.y * 64;
  const int chunk0 = blockIdx.x * chunks_per_block;
  const int wr  = (w >> 1) * 32;   // wave row offset within block tile
  const int wcg = (w & 1) * 4;     // wave col-group base (x16 cols)

  // ---- A fragments: h rows, hi/lo bf16 split, live in regs for all chunks
  bf16x8 Ahi[2][4], Alo[2][4];
  #pragma unroll
  for (int f = 0; f < 2; ++f) {
    int row = row0 + wr + f * 16 + lr;
    const float* hr = h + (size_t)row * KD + lk * 8;
    #pragma unroll
    for (int ks = 0; ks < 4; ++ks) {
      float4 xa = *(const float4*)(hr + ks * 32);
      float4 xb = *(const float4*)(hr + ks * 32 + 4);
      float xs[8] = {xa.x, xa.y, xa.z, xa.w, xb.x, xb.y, xb.z, xb.w};
      bf16x8 ah, al;
      #pragma unroll
      for (int j = 0; j < 8; ++j) {
        unsigned short hb = f2bf(xs[j]);
        float hf = __uint_as_float((unsigned)hb << 16);
        ah[j] = (short)hb;
        al[j] = (short)f2bf(xs[j] - hf);
      }
      Ahi[f][ks] = ah; Alo[f][ks] = al;
    }
  }

  float m[2][4];
  #pragma unroll
  for (int f = 0; f < 2; ++f)
    #pragma unroll
    for (int r = 0; r < 4; ++r)
      m[f][r] = hnorm[row0 + wr + f * 16 + lk * 4 + r];

  float sacc[2][4] = {{0.f,0.f,0.f,0.f},{0.f,0.f,0.f,0.f}};
  float qacc[2][4] = {{0.f,0.f,0.f,0.f},{0.f,0.f,0.f,0.f}};

  const int sw = (lr & 7) << 4;

  for (int ck = 0; ck < chunks_per_block; ++ck) {
    __syncthreads();  // previous chunk fully consumed
    {
      const char* gk = keys2 + (size_t)(chunk0 + ck) * 65536 + (size_t)t * 16;
      char* lk_ = (char*)&s_k[0][0][0] + t * 16;
      #pragma unroll
      for (int it = 0; it < 16; ++it)
        __builtin_amdgcn_global_load_lds(
            (const __attribute__((address_space(1))) unsigned int*)(gk + it * 4096),
            (__attribute__((address_space(3))) unsigned int*)(lk_ + it * 4096),
            16, 0, 0);
      if (t < KG2) s_v[t] = values[(size_t)(chunk0 + ck) * KG2 + t];
    }
    __syncthreads();  // vmcnt/lgkm drained by compiler before barrier

    #pragma unroll
    for (int g = 0; g < 4; ++g) {
      const int c = (wcg + g) * 16 + lr;
      const char* bbase = (const char*)&s_k[0][0][0] + c * 256;
      f32x4 C0 = {0.f, 0.f, 0.f, 0.f};
      f32x4 C1 = {0.f, 0.f, 0.f, 0.f};
      #pragma unroll
      for (int ks = 0; ks < 4; ++ks) {
        const int off = (ks * 64 + lk * 16) ^ sw;
        bf16x8 Bh = *(const bf16x8*)(bbase + off);
        bf16x8 Bl = *(const bf16x8*)(bbase + 32768 + off);
        C0 = mfma16(Ahi[0][ks], Bh, C0);
        C1 = mfma16(Ahi[1][ks], Bh, C1);
        C0 = mfma16(Alo[0][ks], Bh, C0);
        C1 = mfma16(Alo[1][ks], Bh, C1);
        C0 = mfma16(Ahi[0][ks], Bl, C0);
        C1 = mfma16(Ahi[1][ks], Bl, C1);
      }
      float v = s_v[c];
      #pragma unroll
      for (int r = 0; r < 4; ++r) {
        float e0 = exp2f(C0[r] - m[0][r]);
        sacc[0][r] += e0; qacc[0][r] = fmaf(e0, v, qacc[0][r]);
        float e1 = exp2f(C1[r] - m[1][r]);
        sacc[1][r] += e1; qacc[1][r] = fmaf(e1, v, qacc[1][r]);
      }
    }
  }

  #pragma unroll
  for (int f = 0; f < 2; ++f)
    #pragma unroll
    for (int r = 0; r < 4; ++r) {
      float s = sacc[f][r], q = qacc[f][r];
      #pragma unroll
      for (int off = 8; off; off >>= 1) {
        s += __shfl_down(s, off, 16);
        q += __shfl_down(q, off, 16);
      }
      if (lr == 0) {
        int row = row0 + wr + f * 16 + lk * 4 + r;
        atomicAdd(&accum[(size_t)row * 2 + 0], s);
        atomicAdd(&accum[(size_t)row * 2 + 1], q);
      }
    }
}

// ---------------------------------------------------------------------------
// Kernel 2 (fp32 fallback if ws too small): round-1 structure, exp2 domain.
// ---------------------------------------------------------------------------
#define TB 64
#define KG 64
#define SPAD 132

__global__ __launch_bounds__(256) void score_f32_kernel(
    const float* __restrict__ h, const float* __restrict__ hnorm,
    const float* __restrict__ keys, const float* __restrict__ values,
    float* __restrict__ accum, int keys_per_block) {
  __shared__ float s_h[TB][SPAD];
  __shared__ float s_k[KG][SPAD];
  __shared__ float s_v[KG];

  const int t  = threadIdx.x;
  const int kq = t & 15;
  const int rq = t >> 4;
  const int row0 = blockIdx.y * TB;
  const size_t key0 = (size_t)blockIdx.x * (size_t)keys_per_block;

  {
    const float4* g = (const float4*)(h + (size_t)row0 * KD);
    for (int i = t; i < TB * KD / 4; i += 256) {
      int r = i >> 5, d4 = i & 31;
      *(float4*)&s_h[r][d4 * 4] = g[i];
    }
  }

  float m[4];
  #pragma unroll
  for (int i = 0; i < 4; ++i) m[i] = hnorm[row0 + rq * 4 + i];

  float s_acc[4] = {0.f, 0.f, 0.f, 0.f};
  float q_acc[4] = {0.f, 0.f, 0.f, 0.f};

  for (int kg = 0; kg < keys_per_block; kg += KG) {
    __syncthreads();
    {
      const float4* g = (const float4*)(keys + (key0 + kg) * KD);
      for (int i = t; i < KG * KD / 4; i += 256) {
        int ki = i >> 5, d4 = i & 31;
        *(float4*)&s_k[ki][d4 * 4] = g[i];
      }
      if (t < KG) s_v[t] = values[key0 + kg + t];
    }
    __syncthreads();

    float sc[4][4];
    #pragma unroll
    for (int i = 0; i < 4; ++i)
      #pragma unroll
      for (int j = 0; j < 4; ++j) sc[i][j] = 0.f;

    for (int d = 0; d < KD; d += 4) {
      float4 kv[4], hv[4];
      #pragma unroll
      for (int j = 0; j < 4; ++j) kv[j] = *(const float4*)&s_k[kq + 16 * j][d];
      #pragma unroll
      for (int i = 0; i < 4; ++i) hv[i] = *(const float4*)&s_h[rq * 4 + i][d];
      #pragma unroll
      for (int i = 0; i < 4; ++i)
        #pragma unroll
        for (int j = 0; j < 4; ++j)
          sc[i][j] += hv[i].x * kv[j].x + hv[i].y * kv[j].y
                    + hv[i].z * kv[j].z + hv[i].w * kv[j].w;
    }

    #pragma unroll
    for (int j = 0; j < 4; ++j) {
      float v = s_v[kq + 16 * j];
      #pragma unroll
      for (int i = 0; i < 4; ++i) {
        float e = exp2f(sc[i][j] - m[i]);
        s_acc[i] += e;
        q_acc[i] += e * v;
      }
    }
  }

  #pragma unroll
  for (int i = 0; i < 4; ++i) {
    float s = s_acc[i], q = q_acc[i];
    #pragma unroll
    for (int off = 8; off; off >>= 1) {
      s += __shfl_down(s, off, 16);
      q += __shfl_down(q, off, 16);
    }
    if (kq == 0) {
      atomicAdd(&accum[(size_t)(row0 + rq * 4 + i) * 2 + 0], s);
      atomicAdd(&accum[(size_t)(row0 + rq * 4 + i) * 2 + 1], q);
    }
  }
}

// ---------------------------------------------------------------------------
__global__ void finalize_kernel(const float* __restrict__ accum,
                                float* __restrict__ out) {
  int b = blockIdx.x * 256 + threadIdx.x;
  if (b < B_ROWS) out[b] = accum[(size_t)b * 2 + 1] / accum[(size_t)b * 2 + 0];
}

// ---------------------------------------------------------------------------
extern "C" void kernel_launch(void* const* d_in, const int* in_sizes, int n_in,
                              void* d_out, int out_size, void* d_ws, size_t ws_size,
                              hipStream_t stream) {
  const float* obs      = (const float*)d_in[0];
  const float* action   = (const float*)d_in[1];
  const float* pred_W   = (const float*)d_in[2];
  const float* pred_b   = (const float*)d_in[3];
  const float* t1_W     = (const float*)d_in[4];
  const float* t1_b     = (const float*)d_in[5];
  const float* t2_W     = (const float*)d_in[6];
  const float* t2_b     = (const float*)d_in[7];
  const float* keys     = (const float*)d_in[8];
  const float* values   = (const float*)d_in[9];
  const float* log_temp = (const float*)d_in[10];
  float* out = (float*)d_out;

  float* h     = (float*)d_ws;             // 1024*128 f32 = 512 KB
  float* hnorm = h + (size_t)B_ROWS * KD;  // 4 KB
  float* accum = hnorm + B_ROWS;           // 8 KB
  const size_t KEYS2_OFF = 1 << 20;        // 1 MB
  const size_t KEYS2_BYTES = (size_t)CAP * KD * 2 * 2;  // 64 MB
  char* keys2 = (char*)d_ws + KEYS2_OFF;
  const bool big_ws = ws_size >= KEYS2_OFF + KEYS2_BYTES;

  hipMemsetAsync(accum, 0, (size_t)B_ROWS * 2 * sizeof(float), stream);

  hipLaunchKernelGGL(mlp_kernel, dim3(B_ROWS / MLP_ROWS), dim3(256), 0, stream,
                     obs, action, pred_W, pred_b, t1_W, t1_b, t2_W, t2_b,
                     log_temp, h, hnorm);

  if (big_ws) {
    hipLaunchKernelGGL(preconv_kernel, dim3(CAP * KD / 4 / 256), dim3(256), 0,
                       stream, keys, keys2);
    const int XB = 32;                      // key-chunk blocks
    hipLaunchKernelGGL(score_mfma_kernel, dim3(XB, B_ROWS / 64), dim3(256), 0,
                       stream, h, hnorm, keys2, values, accum,
                       (CAP / KG2) / XB);
  } else {
    const int C_CHUNKS = 32;
    hipLaunchKernelGGL(score_f32_kernel, dim3(C_CHUNKS, B_ROWS / TB), dim3(256),
                       0, stream, h, hnorm, keys, values, accum,
                       CAP / C_CHUNKS);
  }

  hipLaunchKernelGGL(finalize_kernel, dim3(4), dim3(256), 0, stream, accum, out);
}